// Round 2
// baseline (518.792 us; speedup 1.0000x reference)
//
#include <hip/hip_runtime.h>

typedef unsigned short u16;
typedef __attribute__((ext_vector_type(8))) short short8;   // 8 x bf16 (4 VGPRs)
typedef __attribute__((ext_vector_type(4))) float f32x4;    // MFMA accumulator

__device__ __forceinline__ u16 f2bf(float f) {
  union { float f; unsigned u; } c; c.f = f;
  unsigned u = c.u;
  return (u16)((u + 0x7FFFu + ((u >> 16) & 1u)) >> 16);     // round-nearest-even
}

// async global->LDS, 16B per lane; LDS dest = wave-uniform base + lane*16
__device__ __forceinline__ void gload_lds16(const void* g, void* l) {
  __builtin_amdgcn_global_load_lds(
      (const __attribute__((address_space(1))) unsigned int*)g,
      (__attribute__((address_space(3))) unsigned int*)l, 16, 0, 0);
}

// ---------------------------------------------------------------- prep kernels
__global__ __launch_bounds__(256) void cvt_x_kernel(const float* __restrict__ x,
                                                    u16* __restrict__ xb) {
  int i = blockIdx.x * 256 + threadIdx.x;          // grid sized exactly: 4194304/4
  float4 v = ((const float4*)x)[i];
  uint2 st;
  st.x = (unsigned)f2bf(v.x) | ((unsigned)f2bf(v.y) << 16);
  st.y = (unsigned)f2bf(v.z) | ((unsigned)f2bf(v.w) << 16);
  ((uint2*)xb)[i] = st;
}

// Wt[n][k] = bf16(W[k][n]), K=512. Tiled 32x32 through LDS: both sides coalesced.
__global__ __launch_bounds__(256) void transp_kernel(const float* __restrict__ W,
                                                     u16* __restrict__ Wt, int NC) {
  __shared__ float T[32][33];
  const int n0 = blockIdx.x * 32, k0 = blockIdx.y * 32;
  const int tx = threadIdx.x & 31, ty = threadIdx.x >> 5;
#pragma unroll
  for (int i = 0; i < 4; i++)
    T[ty + 8 * i][tx] = W[(size_t)(k0 + ty + 8 * i) * NC + n0 + tx];
  __syncthreads();
#pragma unroll
  for (int i = 0; i < 4; i++)
    Wt[(size_t)(n0 + ty + 8 * i) * 512 + k0 + tx] = f2bf(T[tx][ty + 8 * i]);
}

// ---------------------------------------------------------------- GEMM (K=512)
// C[M x NC] = A[M x 512] * W[512 x NC]; m97 structure: 128x128 tile, BK=64,
// global_load_lds width-16 staging, 4 waves in 2x2, 64x64 quadrant each.
// MODE 0: QKV epilogue -> scatter q/k (head-major) + V transposed, +b_qkv
// MODE 1: out-proj epilogue -> fp32 out, +b_o
template<int MODE>
__global__ __launch_bounds__(256) void gemm_kernel(
    const u16* __restrict__ A, const u16* __restrict__ Bt,
    const float* __restrict__ biasv,
    u16* __restrict__ qb, u16* __restrict__ kb, u16* __restrict__ vtb,
    float* __restrict__ outp) {
  __shared__ u16 As[128 * 64];
  __shared__ u16 Bs[128 * 64];
  const int tid = threadIdx.x;
  const int lane = tid & 63;
  const int w = tid >> 6, wm = w >> 1, wn = w & 1;
  const int m0 = blockIdx.y * 128, n0 = blockIdx.x * 128;
  const int lr = lane >> 3, ls = lane & 7;   // staging: 8 rows x 8 segs per instr
  const int lm = lane & 15, lg = lane >> 4;
  f32x4 acc[4][4] = {};

  for (int k0 = 0; k0 < 512; k0 += 64) {
    __syncthreads();
#pragma unroll
    for (int j = 0; j < 4; j++) {
      const int rowb = w * 32 + j * 8;
      gload_lds16(&A[(size_t)(m0 + rowb + lr) * 512 + k0 + ls * 8], &As[rowb * 64]);
      gload_lds16(&Bt[(size_t)(n0 + rowb + lr) * 512 + k0 + ls * 8], &Bs[rowb * 64]);
    }
    __syncthreads();   // drains vmcnt: async LDS data visible
#pragma unroll
    for (int tc = 0; tc < 2; tc++) {
      short8 af[4], bf[4];
#pragma unroll
      for (int t = 0; t < 4; t++) {
        af[t] = *(const short8*)&As[(wm * 64 + t * 16 + lm) * 64 + tc * 32 + lg * 8];
        bf[t] = *(const short8*)&Bs[(wn * 64 + t * 16 + lm) * 64 + tc * 32 + lg * 8];
      }
#pragma unroll
      for (int mt = 0; mt < 4; mt++)
#pragma unroll
        for (int nt = 0; nt < 4; nt++)
          acc[mt][nt] = __builtin_amdgcn_mfma_f32_16x16x32_bf16(af[mt], bf[nt], acc[mt][nt], 0, 0, 0);
    }
  }

#pragma unroll
  for (int mt = 0; mt < 4; mt++) {
#pragma unroll
    for (int nt = 0; nt < 4; nt++) {
      const int col = n0 + wn * 64 + nt * 16 + lm;
      const float bv = biasv[col];
#pragma unroll
      for (int r2 = 0; r2 < 4; r2++) {
        const int row = m0 + wm * 64 + mt * 16 + lg * 4 + r2;  // C/D: col=lane&15, row=(lane>>4)*4+reg
        const float v = acc[mt][nt][r2] + bv;
        if (MODE == 0) {
          const int h = col / 192, rem = col % 192;   // qkv reshape: col = h*192 + which*64 + t
          const int which = rem >> 6, t = rem & 63;
          const int b = row >> 10, n = row & 1023;
          const u16 bb = f2bf(v);
          if (which == 0)      qb[((size_t)(b * 8 + h) * 1024 + n) * 64 + t] = bb;
          else if (which == 1) kb[((size_t)(b * 8 + h) * 1024 + n) * 64 + t] = bb;
          else                 vtb[((size_t)(b * 8 + h) * 64 + t) * 1024 + n] = bb;
        } else {
          outp[(size_t)row * 512 + col] = v;
        }
      }
    }
  }
}

// ---------------------------------------------------------------- attention
// grid (N/16, B), block 512 = 8 waves; wave h = head h, 16 q-rows per block.
// 512 blocks -> 2 blocks/CU (16 waves/CU): one block computes while the other
// waits on its bias-staging barrier. Bias loads are float4 (all 8 heads),
// perfectly coalesced; LDS transpose to [h][q][k], plane stride 544 + pad 34
// makes softmax reads 2-way (free) bank access.
__global__ __launch_bounds__(512) void attn_kernel(
    const u16* __restrict__ qb, const u16* __restrict__ kb,
    const u16* __restrict__ vtb, const float* __restrict__ bias,
    u16* __restrict__ yb) {
  __shared__ float biasS[8 * 544];       // [h][q*34 + k], 17408 B
  __shared__ u16 Ps[8 * 16 * 40];        // per-wave P tile (16 x 32, row stride 40), 10240 B
  const int tid = threadIdx.x;
  const int lane = tid & 63;
  const int h = tid >> 6;
  const int b = blockIdx.y;
  const int q0 = blockIdx.x * 16;
  const size_t bh = (size_t)b * 8 + h;
  const u16* Q  = qb  + bh * (1024 * 64);
  const u16* K  = kb  + bh * (1024 * 64);
  const u16* VT = vtb + bh * (64 * 1024);
  const int lm = lane & 15, lg = lane >> 4;

  // Q fragment in registers for whole kernel (A-layout: m=lane&15, k=lg*8+j)
  short8 aq[2];
#pragma unroll
  for (int tc = 0; tc < 2; tc++)
    aq[tc] = *(const short8*)&Q[(size_t)(q0 + lm) * 64 + tc * 32 + lg * 8];

  f32x4 o[4] = {};
  float mrow[4], lrow[4];
#pragma unroll
  for (int r2 = 0; r2 < 4; r2++) { mrow[r2] = -1e30f; lrow[r2] = 0.f; }

  const float SC   = 0.125f * 1.4426950408889634f;  // 1/sqrt(64) * log2(e)
  const float LG2E = 1.4426950408889634f;

  // bias staging: 1024 float4 per 32-k chunk = 16 q x 32 k x {head-half}.
  // idx -> (q = idx>>6, k = (idx&63)>>1, half = idx&1); consecutive tid =
  // consecutive float4 addresses -> fully coalesced.
  const float4* b4 = (const float4*)bias;
  int qi[2], kk[2], hf[2];
#pragma unroll
  for (int p = 0; p < 2; p++) {
    const int idx = p * 512 + tid;
    qi[p] = idx >> 6; kk[p] = (idx & 63) >> 1; hf[p] = idx & 1;
  }
  float4 pre[2];
#pragma unroll
  for (int p = 0; p < 2; p++)
    pre[p] = b4[((size_t)(b * 1024 + q0 + qi[p]) * 1024 + kk[p]) * 2 + hf[p]];

  for (int kc = 0; kc < 1024; kc += 32) {
    __syncthreads();
#pragma unroll
    for (int p = 0; p < 2; p++) {
      const float* pf = (const float*)&pre[p];
      const int base = qi[p] * 34 + kk[p];
#pragma unroll
      for (int j = 0; j < 4; j++)
        biasS[(hf[p] * 4 + j) * 544 + base] = pf[j];
    }
    __syncthreads();
    if (kc + 32 < 1024) {              // prefetch next chunk into registers
#pragma unroll
      for (int p = 0; p < 2; p++)
        pre[p] = b4[((size_t)(b * 1024 + q0 + qi[p]) * 1024 + (kc + 32) + kk[p]) * 2 + hf[p]];
    }

    // S = Q K^T for 16 q x 32 k   (B-layout: n=lane&15 -> key, k=lg*8+j -> t)
    f32x4 s2[2];
#pragma unroll
    for (int kt = 0; kt < 2; kt++) {
      short8 bk[2];
#pragma unroll
      for (int tc = 0; tc < 2; tc++)
        bk[tc] = *(const short8*)&K[(size_t)(kc + kt * 16 + lm) * 64 + tc * 32 + lg * 8];
      f32x4 c = {0.f, 0.f, 0.f, 0.f};
      c = __builtin_amdgcn_mfma_f32_16x16x32_bf16(aq[0], bk[0], c, 0, 0, 0);
      c = __builtin_amdgcn_mfma_f32_16x16x32_bf16(aq[1], bk[1], c, 0, 0, 0);
      s2[kt] = c;
    }

    // online softmax (base-2 domain); P -> per-wave LDS (no barrier: per-wave DS order)
    float pv2[2][4];
#pragma unroll
    for (int kt = 0; kt < 2; kt++)
#pragma unroll
      for (int r2 = 0; r2 < 4; r2++)
        pv2[kt][r2] = s2[kt][r2] * SC +
                      biasS[h * 544 + (lg * 4 + r2) * 34 + kt * 16 + lm] * LG2E;
    float rmax[4];
#pragma unroll
    for (int r2 = 0; r2 < 4; r2++) rmax[r2] = fmaxf(pv2[0][r2], pv2[1][r2]);
#pragma unroll
    for (int d = 1; d < 16; d <<= 1)
#pragma unroll
      for (int r2 = 0; r2 < 4; r2++)
        rmax[r2] = fmaxf(rmax[r2], __shfl_xor(rmax[r2], d));
    float alpha[4];
#pragma unroll
    for (int r2 = 0; r2 < 4; r2++) {
      const float mn = fmaxf(mrow[r2], rmax[r2]);
      alpha[r2] = exp2f(mrow[r2] - mn);
      mrow[r2] = mn;
    }
    float rsum[4] = {0.f, 0.f, 0.f, 0.f};
#pragma unroll
    for (int kt = 0; kt < 2; kt++)
#pragma unroll
      for (int r2 = 0; r2 < 4; r2++) {
        const float p = exp2f(pv2[kt][r2] - mrow[r2]);
        pv2[kt][r2] = p;
        rsum[r2] += p;
      }
#pragma unroll
    for (int d = 1; d < 16; d <<= 1)
#pragma unroll
      for (int r2 = 0; r2 < 4; r2++)
        rsum[r2] += __shfl_xor(rsum[r2], d);
#pragma unroll
    for (int r2 = 0; r2 < 4; r2++)
      lrow[r2] = lrow[r2] * alpha[r2] + rsum[r2];
#pragma unroll
    for (int nt = 0; nt < 4; nt++)
#pragma unroll
      for (int r2 = 0; r2 < 4; r2++)
        o[nt][r2] *= alpha[r2];
#pragma unroll
    for (int kt = 0; kt < 2; kt++)
#pragma unroll
      for (int r2 = 0; r2 < 4; r2++)
        Ps[h * 640 + (lg * 4 + r2) * 40 + kt * 16 + lm] = f2bf(pv2[kt][r2]);

    // PV: A = P (LDS round-trip C->A layout), B = V^T rows (contiguous 16B)
    short8 bv[4];
#pragma unroll
    for (int nt = 0; nt < 4; nt++)
      bv[nt] = *(const short8*)&VT[(size_t)(nt * 16 + lm) * 1024 + kc + lg * 8];
    short8 ap = *(const short8*)&Ps[h * 640 + lm * 40 + lg * 8];
#pragma unroll
    for (int nt = 0; nt < 4; nt++)
      o[nt] = __builtin_amdgcn_mfma_f32_16x16x32_bf16(ap, bv[nt], o[nt], 0, 0, 0);
  }

  // epilogue: y = O / l, bf16, layout [token][h*64 + t]
#pragma unroll
  for (int nt = 0; nt < 4; nt++)
#pragma unroll
    for (int r2 = 0; r2 < 4; r2++) {
      const int row = q0 + lg * 4 + r2;
      const float yv = o[nt][r2] / lrow[r2];
      yb[((size_t)(b * 1024 + row)) * 512 + h * 64 + nt * 16 + lm] = f2bf(yv);
    }
}

// ---------------------------------------------------------------- launch
extern "C" void kernel_launch(void* const* d_in, const int* in_sizes, int n_in,
                              void* d_out, int out_size, void* d_ws, size_t ws_size,
                              hipStream_t stream) {
  const float* x    = (const float*)d_in[0];
  const float* bias = (const float*)d_in[1];
  const float* Wqkv = (const float*)d_in[2];
  const float* bqkv = (const float*)d_in[3];
  const float* Wo   = (const float*)d_in[4];
  const float* bo   = (const float*)d_in[5];
  float* out = (float*)d_out;

  char* p = (char*)d_ws;
  u16* xb    = (u16*)p; p += (size_t)8192 * 512 * 2;        // 8 MB
  u16* wqkvT = (u16*)p; p += (size_t)1536 * 512 * 2;        // 1.5 MB
  u16* woT   = (u16*)p; p += (size_t)512 * 512 * 2;         // 0.5 MB
  u16* qB    = (u16*)p; p += (size_t)8 * 8 * 1024 * 64 * 2; // 8 MB
  u16* kB    = (u16*)p; p += (size_t)8 * 8 * 1024 * 64 * 2; // 8 MB
  u16* vtB   = (u16*)p; p += (size_t)8 * 8 * 64 * 1024 * 2; // 8 MB
  u16* yB    = (u16*)p; p += (size_t)8192 * 512 * 2;        // 8 MB  (total ~44 MB)

  cvt_x_kernel<<<4096, 256, 0, stream>>>(x, xb);
  transp_kernel<<<dim3(48, 16), 256, 0, stream>>>(Wqkv, wqkvT, 1536);
  transp_kernel<<<dim3(16, 16), 256, 0, stream>>>(Wo, woT, 512);
  gemm_kernel<0><<<dim3(12, 64), 256, 0, stream>>>(xb, wqkvT, bqkv, qB, kB, vtB, nullptr);
  attn_kernel<<<dim3(64, 8), 512, 0, stream>>>(qB, kB, vtB, bias, yB);
  gemm_kernel<1><<<dim3(4, 64), 256, 0, stream>>>(yB, woT, bo, nullptr, nullptr, nullptr, out);
}